// Round 1
// baseline (10164.552 us; speedup 1.0000x reference)
//
#include <hip/hip_runtime.h>
#include <math.h>

#define N_    32
#define CIN   128
#define H_    56
#define W_    56
#define COUT  256
#define OH    28
#define OW    28
#define EPS_  0.007f

// ws layout (floats): [0] = alpha scale, [16..16+256) = w_sq, then patch_sq, then yat buffer
#define WSQ_OFF 16
#define PSQ_OFF (WSQ_OFF + COUT)            // 272
#define YAT_OFF (PSQ_OFF + N_ * OH * OW)    // 272 + 25088 = 25360

// ---------------- per-filter squared norm + alpha scale ----------------
__global__ void k_wsq_scale(const float* __restrict__ w_yat,
                            const float* __restrict__ alpha,
                            float* __restrict__ ws) {
    int co = blockIdx.x * blockDim.x + threadIdx.x;
    if (co < COUT) {
        const float* wc = w_yat + (size_t)co * CIN * 9;
        float s = 0.f;
        for (int i = 0; i < CIN * 9; ++i) s += wc[i] * wc[i];
        ws[WSQ_OFF + co] = s;
    }
    if (co == 0) {
        // (sqrt(256)/log1p(256))**alpha
        ws[0] = powf(16.0f / log1pf(256.0f), alpha[0]);
    }
}

// ---------------- per-patch squared norm (3x3, stride 2, pad 1) ----------------
__global__ void k_psq(const float* __restrict__ x, float* __restrict__ ws) {
    int idx = blockIdx.x * blockDim.x + threadIdx.x;
    if (idx >= N_ * OH * OW) return;
    int ow = idx % OW;
    int t  = idx / OW;
    int oh = t % OH;
    int n  = t / OH;

    const float* xb = x + (size_t)n * CIN * H_ * W_;
    int ih0 = oh * 2 - 1, iw0 = ow * 2 - 1;
    float s = 0.f;
    for (int ci = 0; ci < CIN; ++ci) {
        const float* xc = xb + (size_t)ci * H_ * W_;
#pragma unroll
        for (int kh = 0; kh < 3; ++kh) {
            int ih = ih0 + kh;
            if ((unsigned)ih >= H_) continue;
            const float* row = xc + (size_t)ih * W_;
#pragma unroll
            for (int kw = 0; kw < 3; ++kw) {
                int iw = iw0 + kw;
                if ((unsigned)iw >= W_) continue;
                float v = row[iw];
                s += v * v;
            }
        }
    }
    ws[PSQ_OFF + idx] = s;
}

// ---------------- YAT conv (dot, dist, y) + 1x1 stride-2 shortcut ----------------
__global__ void k_yat(const float* __restrict__ x,
                      const float* __restrict__ w_yat,
                      const float* __restrict__ w_short,
                      float* __restrict__ ws,
                      float* __restrict__ out) {
    int idx = blockIdx.x * blockDim.x + threadIdx.x;   // over N*COUT*OH*OW
    int ow = idx % OW;
    int t  = idx / OW;
    int oh = t % OH; t /= OH;
    int co = t % COUT;
    int n  = t / COUT;

    const float* xb  = x + (size_t)n * CIN * H_ * W_;
    const float* wb  = w_yat + (size_t)co * CIN * 9;
    const float* wsh = w_short + (size_t)co * CIN;

    int ih0 = oh * 2 - 1, iw0 = ow * 2 - 1;
    int ihc = oh * 2, iwc = ow * 2;   // shortcut tap (always in range)

    float dot = 0.f, idv = 0.f;
    for (int ci = 0; ci < CIN; ++ci) {
        const float* xc = xb + (size_t)ci * H_ * W_;
        const float* wc = wb + ci * 9;
#pragma unroll
        for (int kh = 0; kh < 3; ++kh) {
            int ih = ih0 + kh;
            if ((unsigned)ih >= H_) continue;
            const float* row = xc + (size_t)ih * W_;
#pragma unroll
            for (int kw = 0; kw < 3; ++kw) {
                int iw = iw0 + kw;
                if ((unsigned)iw >= W_) continue;
                dot += row[iw] * wc[kh * 3 + kw];
            }
        }
        idv += xc[(size_t)ihc * W_ + iwc] * wsh[ci];
    }

    float psq   = ws[PSQ_OFF + (n * OH + oh) * OW + ow];
    float wsq   = ws[WSQ_OFF + co];
    float scale = ws[0];
    float dist  = psq + wsq - 2.0f * dot + EPS_;
    float y     = dot * dot / dist * scale;

    ws[YAT_OFF + idx] = y;   // yat intermediate
    out[idx]          = idv; // identity (accumulated into by k_lin)
}

// ---------------- plain 3x3 conv (stride 1, pad 1) over yat, += into out ----------------
__global__ void k_lin(const float* __restrict__ yat,
                      const float* __restrict__ w_lin,
                      float* __restrict__ out) {
    int idx = blockIdx.x * blockDim.x + threadIdx.x;   // over N*COUT*OH*OW
    int ow = idx % OW;
    int t  = idx / OW;
    int oh = t % OH; t /= OH;
    int co = t % COUT;
    int n  = t / COUT;

    const float* yb = yat + (size_t)n * COUT * OH * OW;
    const float* wb = w_lin + (size_t)co * COUT * 9;

    float acc = 0.f;
    for (int ci = 0; ci < COUT; ++ci) {
        const float* yc = yb + (size_t)ci * OH * OW;
        const float* wc = wb + ci * 9;
#pragma unroll
        for (int kh = 0; kh < 3; ++kh) {
            int ih = oh - 1 + kh;
            if ((unsigned)ih >= OH) continue;
            const float* row = yc + (size_t)ih * OW;
#pragma unroll
            for (int kw = 0; kw < 3; ++kw) {
                int iw = ow - 1 + kw;
                if ((unsigned)iw >= OW) continue;
                acc += row[iw] * wc[kh * 3 + kw];
            }
        }
    }
    out[idx] += acc;
}

extern "C" void kernel_launch(void* const* d_in, const int* in_sizes, int n_in,
                              void* d_out, int out_size, void* d_ws, size_t ws_size,
                              hipStream_t stream) {
    const float* x       = (const float*)d_in[0];
    const float* w_yat   = (const float*)d_in[1];
    const float* alpha   = (const float*)d_in[2];
    const float* w_lin   = (const float*)d_in[3];
    const float* w_short = (const float*)d_in[4];
    float* out = (float*)d_out;
    float* ws  = (float*)d_ws;

    const int total = N_ * COUT * OH * OW;   // 6,422,528 (divisible by 256)

    k_wsq_scale<<<1, 256, 0, stream>>>(w_yat, alpha, ws);
    k_psq<<<(N_ * OH * OW + 255) / 256, 256, 0, stream>>>(x, ws);
    k_yat<<<total / 256, 256, 0, stream>>>(x, w_yat, w_short, ws, out);
    k_lin<<<total / 256, 256, 0, stream>>>(ws + YAT_OFF, w_lin, out);
}

// Round 2
// 257.330 us; speedup vs baseline: 39.5001x; 39.5001x over previous
//
#include <hip/hip_runtime.h>
#include <math.h>

#define N_    32
#define CIN   128
#define H_    56
#define W_    56
#define COUT  256
#define OH    28
#define OW    28
#define M_    (N_ * OH * OW)      // 25088
#define EPS_  0.007f

typedef unsigned short U16;
typedef float f32x4  __attribute__((ext_vector_type(4)));
typedef short bf16x8 __attribute__((ext_vector_type(8)));

// ws float-region layout
#define SCALE_IDX 0
#define WSQ_IDX   16            // 256 floats
#define PSQ_IDX   512           // 25088 floats
#define U16_BYTE_OFF 102400     // = 25600 floats, 256B aligned

__device__ __forceinline__ U16 f2bf(float f) {
    unsigned int u = __builtin_bit_cast(unsigned int, f);
    u = (u + 0x7fffu + ((u >> 16) & 1u)) >> 16;   // RNE
    return (U16)u;
}
__device__ __forceinline__ float b2f(U16 h) {
    unsigned int u = ((unsigned int)h) << 16;
    return __builtin_bit_cast(float, u);
}

// ---------------- weight reorder to B'[co][k] bf16 ----------------
// B1: k = (kh*3+kw)*128 + ci  (w_yat)   294912 elems
// B3: k = (kh*3+kw)*256 + cy  (w_lin)   589824 elems
// B2: k = ci                  (w_short)  32768 elems
__global__ void k_prep_w(const float* __restrict__ w_yat,
                         const float* __restrict__ w_lin,
                         const float* __restrict__ w_short,
                         U16* __restrict__ B1, U16* __restrict__ B3, U16* __restrict__ B2) {
    int idx = blockIdx.x * 256 + threadIdx.x;
    if (idx < 294912) {
        int co = idx / 1152, k = idx % 1152;
        int khkw = k >> 7, ci = k & 127;
        B1[idx] = f2bf(w_yat[(co * 128 + ci) * 9 + khkw]);
    } else if (idx < 294912 + 589824) {
        int i2 = idx - 294912;
        int co = i2 / 2304, k = i2 % 2304;
        int khkw = k >> 8, cy = k & 255;
        B3[i2] = f2bf(w_lin[(co * 256 + cy) * 9 + khkw]);
    } else {
        int i3 = idx - (294912 + 589824);   // < 32768
        B2[i3] = f2bf(w_short[i3]);
    }
}

// ---------------- per-filter squared norm (exact f32) + alpha scale ----------------
__global__ void k_wsq_scale(const float* __restrict__ w_yat,
                            const float* __restrict__ alpha,
                            float* __restrict__ wsf) {
    int co = threadIdx.x;
    const float* wc = w_yat + (size_t)co * CIN * 9;
    float s = 0.f;
    for (int i = 0; i < CIN * 9; ++i) s += wc[i] * wc[i];
    wsf[WSQ_IDX + co] = s;
    if (co == 0) wsf[SCALE_IDX] = powf(16.0f / log1pf(256.0f), alpha[0]);
}

// ---------------- NCHW f32 -> NHWC bf16 ----------------
__global__ void k_x_t(const float* __restrict__ x, U16* __restrict__ xt) {
    int idx = blockIdx.x * 256 + threadIdx.x;      // 3,211,264 threads
    int flat = idx * 4;
    int w0 = flat % 56;
    int r1 = flat / 56;
    int h  = r1 % 56;
    int r2 = r1 / 56;
    int ci = r2 & 127;
    int n  = r2 >> 7;
    float4 v = *(const float4*)(x + flat);
    size_t base = ((size_t)(n * 56 + h) * 56 + w0) * 128 + ci;
    xt[base]           = f2bf(v.x);
    xt[base + 128]     = f2bf(v.y);
    xt[base + 256]     = f2bf(v.z);
    xt[base + 384]     = f2bf(v.w);
}

// ---------------- per-patch squared norm: one wave per output pixel ----------------
__global__ void k_psq(const U16* __restrict__ xt, float* __restrict__ wsf) {
    int t = threadIdx.x, lane = t & 63, wv = t >> 6;
    int gm = blockIdx.x * 4 + wv;                  // < 25088 exactly
    int ow = gm % 28, tt = gm / 28;
    int oh = tt % 28, n = tt / 28;
    const U16* xb = xt + (size_t)n * 56 * 56 * 128;
    float s = 0.f;
#pragma unroll
    for (int kh = 0; kh < 3; ++kh) {
        int ih = oh * 2 - 1 + kh;
        if ((unsigned)ih >= 56) continue;
#pragma unroll
        for (int kw = 0; kw < 3; ++kw) {
            int iw = ow * 2 - 1 + kw;
            if ((unsigned)iw >= 56) continue;
            unsigned int v = *(const unsigned int*)&xb[(size_t)((ih * 56 + iw) << 7) + lane * 2];
            float f0 = b2f((U16)(v & 0xffff)), f1 = b2f((U16)(v >> 16));
            s += f0 * f0 + f1 * f1;
        }
    }
#pragma unroll
    for (int off = 32; off >= 1; off >>= 1) s += __shfl_xor(s, off);
    if (lane == 0) wsf[PSQ_IDX + gm] = s;
}

// ---------------- generic MFMA implicit-GEMM ----------------
// MODE 0: yat dot conv (3x3 s2 p1 over x_t), epilogue y = dot^2/(psq+wsq-2dot+eps)*scale -> ybuf bf16 [M][256]
// MODE 1: 1x1 s2 shortcut over x_t, epilogue out = v (f32, NCHW)
// MODE 2: 3x3 s1 p1 over ybuf,      epilogue out += v
template<int KTOT, int MODE>
__launch_bounds__(256)
__global__ void k_gemm(const U16* __restrict__ Asrc, const U16* __restrict__ Bp,
                       const float* __restrict__ wsf, U16* __restrict__ ybuf,
                       float* __restrict__ out) {
    __shared__ U16  Abuf[32 * 64];    // [row][64k] with phys-part XOR swizzle
    __shared__ U16  Btb[128 * 64];    // [col][64k] swizzled
    __shared__ float psq_s[32];
    __shared__ float wsq_s[128];

    int t = threadIdx.x, lane = t & 63, wv = t >> 6;
    int bid = blockIdx.x;
    int m0 = (bid >> 1) * 32;
    int co_base = (bid & 1) * 128;

    if (MODE == 0) {
        if (t < 32)        psq_s[t] = wsf[PSQ_IDX + m0 + t];
        else if (t < 160)  wsq_s[t - 32] = wsf[WSQ_IDX + co_base + (t - 32)];
    }
    float scale = (MODE == 0) ? wsf[SCALE_IDX] : 0.f;

    // A-staging coords: thread t owns contiguous LDS slot t (16B); logical part = phys ^ (row&7)
    int arow = t >> 3, aphys = t & 7, aplog = aphys ^ (arow & 7);
    int am = m0 + arow;
    int aow = am % 28, atmp = am / 28;
    int aoh = atmp % 28, an = atmp / 28;

    f32x4 acc[2][2] = {};

    for (int ks = 0; ks < KTOT / 64; ++ks) {
        int k0 = ks * 64;
        // ---- stage A [32][64] ----
        {
            const U16* src = nullptr;
            bool valid = true;
            if (MODE == 0) {
                int khkw = k0 >> 7, ci0 = k0 & 127;
                int kh = khkw / 3, kw = khkw - kh * 3;
                int ih = aoh * 2 - 1 + kh, iw = aow * 2 - 1 + kw;
                valid = ((unsigned)ih < 56) & ((unsigned)iw < 56);
                src = Asrc + (size_t)(((an * 56 + ih) * 56 + iw) << 7) + ci0 + aplog * 8;
            } else if (MODE == 1) {
                src = Asrc + (size_t)(((an * 56 + aoh * 2) * 56 + aow * 2) << 7) + k0 + aplog * 8;
            } else {
                int khkw = k0 >> 8, cy0 = k0 & 255;
                int kh = khkw / 3, kw = khkw - kh * 3;
                int ih = aoh - 1 + kh, iw = aow - 1 + kw;
                valid = ((unsigned)ih < 28) & ((unsigned)iw < 28);
                src = Asrc + (size_t)(((an * 28 + ih) * 28 + iw) << 8) + cy0 + aplog * 8;
            }
            uint4 v = {0, 0, 0, 0};
            if (valid) v = *(const uint4*)src;
            *(uint4*)&Abuf[t * 8] = v;
        }
        // ---- stage Bt [128][64] ----
#pragma unroll
        for (int r2 = 0; r2 < 4; ++r2) {
            int s = r2 * 256 + t;
            int col = s >> 3, phys = s & 7, plog = phys ^ (col & 7);
            const U16* src = Bp + (size_t)(co_base + col) * KTOT + k0 + plog * 8;
            *(uint4*)&Btb[s * 8] = *(const uint4*)src;
        }
        __syncthreads();
        // ---- MFMA ----
#pragma unroll
        for (int kk = 0; kk < 2; ++kk) {
            bf16x8 af[2], bfr[2];
#pragma unroll
            for (int i = 0; i < 2; ++i) {
                int row = i * 16 + (lane & 15);
                int pp = (kk * 4 + (lane >> 4)) ^ (row & 7);
                af[i] = *(const bf16x8*)&Abuf[(row * 8 + pp) * 8];
            }
#pragma unroll
            for (int j = 0; j < 2; ++j) {
                int col = wv * 32 + j * 16 + (lane & 15);
                int pp = (kk * 4 + (lane >> 4)) ^ (col & 7);
                bfr[j] = *(const bf16x8*)&Btb[(col * 8 + pp) * 8];
            }
#pragma unroll
            for (int i = 0; i < 2; ++i)
#pragma unroll
                for (int j = 0; j < 2; ++j)
                    acc[i][j] = __builtin_amdgcn_mfma_f32_16x16x32_bf16(af[i], bfr[j], acc[i][j], 0, 0, 0);
        }
        __syncthreads();
    }

    // ---- epilogue ----
#pragma unroll
    for (int i = 0; i < 2; ++i)
#pragma unroll
        for (int j = 0; j < 2; ++j)
#pragma unroll
            for (int r = 0; r < 4; ++r) {
                int row = i * 16 + ((lane >> 4) << 2) + r;
                int coll = wv * 32 + j * 16 + (lane & 15);
                float v = acc[i][j][r];
                int m = m0 + row;
                if (MODE == 0) {
                    float dist = psq_s[row] + wsq_s[coll] - 2.0f * v + EPS_;
                    float y = v * v / dist * scale;
                    ybuf[(size_t)m * 256 + co_base + coll] = f2bf(y);
                } else {
                    int ow = m % 28, tt2 = m / 28;
                    int oh = tt2 % 28, n = tt2 / 28;
                    int co = co_base + coll;
                    size_t oidx = ((size_t)(n * 256 + co) * 28 + oh) * 28 + ow;
                    if (MODE == 1) out[oidx] = v;
                    else           out[oidx] += v;
                }
            }
}

extern "C" void kernel_launch(void* const* d_in, const int* in_sizes, int n_in,
                              void* d_out, int out_size, void* d_ws, size_t ws_size,
                              hipStream_t stream) {
    const float* x       = (const float*)d_in[0];
    const float* w_yat   = (const float*)d_in[1];
    const float* alpha   = (const float*)d_in[2];
    const float* w_lin   = (const float*)d_in[3];
    const float* w_short = (const float*)d_in[4];
    float* out = (float*)d_out;
    float* wsf = (float*)d_ws;

    U16* xt = (U16*)((char*)d_ws + U16_BYTE_OFF);
    U16* yb = xt + (size_t)N_ * H_ * W_ * CIN;       // 12,845,056
    U16* B1 = yb + (size_t)M_ * COUT;                 // +6,422,528
    U16* B2 = B1 + 1152 * COUT;                       // +294,912
    U16* B3 = B2 + CIN * COUT;                        // +32,768    (B3: 589,824)

    k_prep_w   <<<3584, 256, 0, stream>>>(w_yat, w_lin, w_short, B1, B3, B2);
    k_wsq_scale<<<1,    256, 0, stream>>>(w_yat, alpha, wsf);
    k_x_t      <<<12544, 256, 0, stream>>>(x, xt);
    k_psq      <<<6272, 256, 0, stream>>>(xt, wsf);

    k_gemm<1152, 0><<<1568, 256, 0, stream>>>(xt, B1, wsf, yb, nullptr);
    k_gemm< 128, 1><<<1568, 256, 0, stream>>>(xt, B2, wsf, nullptr, out);
    k_gemm<2304, 2><<<1568, 256, 0, stream>>>(yb, B3, wsf, nullptr, out);
}

// Round 3
// 168.934 us; speedup vs baseline: 60.1687x; 1.5233x over previous
//
#include <hip/hip_runtime.h>
#include <math.h>

#define N_    32
#define CIN   128
#define H_    56
#define W_    56
#define COUT  256
#define OH    28
#define OW    28
#define M_    (N_ * OH * OW)      // 25088
#define EPS_  0.007f

typedef unsigned short U16;
typedef float f32x4  __attribute__((ext_vector_type(4)));
typedef short bf16x8 __attribute__((ext_vector_type(8)));

// ws float-region layout
#define SCALE_IDX 0
#define ZERO_IDX  8             // wsf[8..15]: 32B zero page for OOB global_load_lds
#define WSQ_IDX   16            // 256 floats
#define PSQ_IDX   512           // 25088 floats
#define U16_BYTE_OFF 102400     // = 25600 floats, 256B aligned

__device__ __forceinline__ U16 f2bf(float f) {
    unsigned int u = __builtin_bit_cast(unsigned int, f);
    u = (u + 0x7fffu + ((u >> 16) & 1u)) >> 16;   // RNE
    return (U16)u;
}
__device__ __forceinline__ float b2f(U16 h) {
    unsigned int u = ((unsigned int)h) << 16;
    return __builtin_bit_cast(float, u);
}

__device__ __forceinline__ void gl_lds16(const U16* g, U16* l) {
    __builtin_amdgcn_global_load_lds((const __attribute__((address_space(1))) void*)g,
                                     (__attribute__((address_space(3))) void*)l, 16, 0, 0);
}

// ---------------- weight reorder to B'[co][k] bf16 ----------------
__global__ void k_prep_w(const float* __restrict__ w_yat,
                         const float* __restrict__ w_lin,
                         const float* __restrict__ w_short,
                         U16* __restrict__ B1, U16* __restrict__ B3, U16* __restrict__ B2) {
    int idx = blockIdx.x * 256 + threadIdx.x;
    if (idx < 294912) {
        int co = idx / 1152, k = idx % 1152;
        int khkw = k >> 7, ci = k & 127;
        B1[idx] = f2bf(w_yat[(co * 128 + ci) * 9 + khkw]);
    } else if (idx < 294912 + 589824) {
        int i2 = idx - 294912;
        int co = i2 / 2304, k = i2 % 2304;
        int khkw = k >> 8, cy = k & 255;
        B3[i2] = f2bf(w_lin[(co * 256 + cy) * 9 + khkw]);
    } else {
        int i3 = idx - (294912 + 589824);   // < 32768
        B2[i3] = f2bf(w_short[i3]);
    }
}

// ---------------- per-filter sqnorm (block per co, coalesced) + scale + zero page ----------------
__global__ void k_wsq_scale(const float* __restrict__ w_yat,
                            const float* __restrict__ alpha,
                            float* __restrict__ wsf) {
    int co = blockIdx.x, t = threadIdx.x, lane = t & 63, wv = t >> 6;
    const float* wc = w_yat + (size_t)co * 1152;
    float s = 0.f;
    for (int i = t; i < 1152; i += 256) { float v = wc[i]; s += v * v; }
#pragma unroll
    for (int off = 32; off >= 1; off >>= 1) s += __shfl_xor(s, off);
    __shared__ float red[4];
    if (lane == 0) red[wv] = s;
    __syncthreads();
    if (t == 0) {
        wsf[WSQ_IDX + co] = red[0] + red[1] + red[2] + red[3];
        if (co == 0) wsf[SCALE_IDX] = powf(16.0f / log1pf(256.0f), alpha[0]);
    }
    if (co == 0 && t >= 8 && t < 16) wsf[ZERO_IDX + (t - 8)] = 0.f;
}

// ---------------- NCHW f32 -> NHWC bf16 (gather-read, coalesced uint4 write) ----------------
__global__ void k_x_t(const float* __restrict__ x, U16* __restrict__ xt) {
    int idx = blockIdx.x * 256 + threadIdx.x;      // 1,605,632 exactly
    int ci8 = idx & 15;
    int px  = idx >> 4;                            // n*3136 + hw
    int n   = px / 3136;
    int hw  = px - n * 3136;
    const float* src = x + ((size_t)n * 128 + ci8 * 8) * 3136 + hw;
    unsigned int o[4];
#pragma unroll
    for (int j = 0; j < 4; ++j) {
        float a = src[(size_t)(2 * j)     * 3136];
        float b = src[(size_t)(2 * j + 1) * 3136];
        o[j] = (unsigned)f2bf(a) | ((unsigned)f2bf(b) << 16);
    }
    *(uint4*)&xt[(size_t)px * 128 + ci8 * 8] = *(const uint4*)o;
}

// ---------------- per-patch squared norm: one wave per output pixel ----------------
__global__ void k_psq(const U16* __restrict__ xt, float* __restrict__ wsf) {
    int t = threadIdx.x, lane = t & 63, wv = t >> 6;
    int gm = blockIdx.x * 4 + wv;                  // < 25088 exactly
    int ow = gm % 28, tt = gm / 28;
    int oh = tt % 28, n = tt / 28;
    const U16* xb = xt + (size_t)n * 56 * 56 * 128;
    float s = 0.f;
#pragma unroll
    for (int kh = 0; kh < 3; ++kh) {
        int ih = oh * 2 - 1 + kh;
        if ((unsigned)ih >= 56) continue;
#pragma unroll
        for (int kw = 0; kw < 3; ++kw) {
            int iw = ow * 2 - 1 + kw;
            if ((unsigned)iw >= 56) continue;
            unsigned int v = *(const unsigned int*)&xb[(size_t)((ih * 56 + iw) << 7) + lane * 2];
            float f0 = b2f((U16)(v & 0xffff)), f1 = b2f((U16)(v >> 16));
            s += f0 * f0 + f1 * f1;
        }
    }
#pragma unroll
    for (int off = 32; off >= 1; off >>= 1) s += __shfl_xor(s, off);
    if (lane == 0) wsf[PSQ_IDX + gm] = s;
}

// ---------------- MFMA implicit-GEMM, BM=64 BN=128 BK=64, global_load_lds staging ----------------
// MODE 0: yat dot conv (3x3 s2 p1 over xt) -> ybuf bf16; fused 1x1 s2 shortcut -> out (f32 NCHW)
// MODE 2: 3x3 s1 p1 over ybuf, out += v
template<int KTOT, int MODE>
__launch_bounds__(256)
__global__ void k_gemm(const U16* __restrict__ Asrc, const U16* __restrict__ Bp,
                       const U16* __restrict__ B2p,
                       const float* __restrict__ wsf, U16* __restrict__ ybuf,
                       float* __restrict__ out) {
    __shared__ U16 Abuf[64 * 64];                       // 8 KB
    __shared__ U16 Btb[128 * 64];                       // 16 KB
    __shared__ U16 Bt2[(MODE == 0) ? 128 * 64 : 8];     // 16 KB (MODE0 only)
    __shared__ float psq_s[64];
    __shared__ float wsq_s[128];

    int t = threadIdx.x, lane = t & 63, wv = t >> 6;
    int wr = wv >> 1, wc = wv & 1;                 // wave tile: rows wr*32, cols wc*64
    int bid = blockIdx.x;
    int m0 = (bid >> 1) * 64;
    int co_base = (bid & 1) * 128;

    if (MODE == 0) {
        if (t < 64)                 psq_s[t] = wsf[PSQ_IDX + m0 + t];
        else if (t < 192)           wsq_s[t - 64] = wsf[WSQ_IDX + co_base + (t - 64)];
    }

    const U16* zptr = (const U16*)&wsf[ZERO_IDX];

    // A-staging: thread t stages rows r0 and r0+32 (16B each), LDS dest linear in t
    int r0 = t >> 3, phys = t & 7;
    int aplog = phys ^ (r0 & 7);                   // (r0+32)&7 == r0&7 -> same swizzle
    int am0 = m0 + r0, am1 = am0 + 32;
    int an0, aoh0, aow0, an1, aoh1, aow1;
    { int tt = am0 / 28; aow0 = am0 - tt * 28; an0 = tt / 28; aoh0 = tt - an0 * 28; }
    { int tt = am1 / 28; aow1 = am1 - tt * 28; an1 = tt / 28; aoh1 = tt - an1 * 28; }

    // B-staging: thread t stages cols c0, c0+32, c0+64, c0+96
    int bcol = t >> 3;
    int bplog = phys ^ (bcol & 7);                 // (bcol+32)&7 == bcol&7
    const U16* bbase = Bp + (size_t)(co_base + bcol) * KTOT + bplog * 8;

    f32x4 acc[2][4] = {};
    f32x4 acc2[2][4] = {};                         // identity (MODE0)

    for (int ks = 0; ks < KTOT / 64; ++ks) {
        int k0 = ks * 64;
        // ---- stage A [64][64] : 2 rounds ----
        if (MODE == 0) {
            int khkw = k0 >> 7, ci0 = k0 & 127;
            int kh = khkw / 3, kw = khkw - 3 * kh;
            int ih0 = aoh0 * 2 - 1 + kh, iw0 = aow0 * 2 - 1 + kw;
            int ih1 = aoh1 * 2 - 1 + kh, iw1 = aow1 * 2 - 1 + kw;
            bool v0 = ((unsigned)ih0 < 56) & ((unsigned)iw0 < 56);
            bool v1 = ((unsigned)ih1 < 56) & ((unsigned)iw1 < 56);
            const U16* s0 = v0 ? Asrc + ((size_t)((an0 * 56 + ih0) * 56 + iw0) << 7) + ci0 + aplog * 8 : zptr;
            const U16* s1 = v1 ? Asrc + ((size_t)((an1 * 56 + ih1) * 56 + iw1) << 7) + ci0 + aplog * 8 : zptr;
            gl_lds16(s0, &Abuf[(size_t)t * 8]);
            gl_lds16(s1, &Abuf[(size_t)(256 + t) * 8]);
        } else {
            int khkw = k0 >> 8, cy0 = k0 & 255;
            int kh = khkw / 3, kw = khkw - 3 * kh;
            int ih0 = aoh0 - 1 + kh, iw0 = aow0 - 1 + kw;
            int ih1 = aoh1 - 1 + kh, iw1 = aow1 - 1 + kw;
            bool v0 = ((unsigned)ih0 < 28) & ((unsigned)iw0 < 28);
            bool v1 = ((unsigned)ih1 < 28) & ((unsigned)iw1 < 28);
            const U16* s0 = v0 ? Asrc + ((size_t)((an0 * 28 + ih0) * 28 + iw0) << 8) + cy0 + aplog * 8 : zptr;
            const U16* s1 = v1 ? Asrc + ((size_t)((an1 * 28 + ih1) * 28 + iw1) << 8) + cy0 + aplog * 8 : zptr;
            gl_lds16(s0, &Abuf[(size_t)t * 8]);
            gl_lds16(s1, &Abuf[(size_t)(256 + t) * 8]);
        }
        // ---- stage B [128][64] : 4 rounds ----
#pragma unroll
        for (int r = 0; r < 4; ++r)
            gl_lds16(bbase + (size_t)r * 32 * KTOT + k0, &Btb[(size_t)(r * 256 + t) * 8]);
        // ---- stage B2 (shortcut) during center-tap K-steps ----
        if (MODE == 0) {
            if (ks == 8 || ks == 9) {
                const U16* b2 = B2p + (size_t)(co_base + bcol) * 128 + (k0 - 512) + bplog * 8;
#pragma unroll
                for (int r = 0; r < 4; ++r)
                    gl_lds16(b2 + (size_t)r * 32 * 128, &Bt2[(size_t)(r * 256 + t) * 8]);
            }
        }
        __syncthreads();
        // ---- MFMA ----
#pragma unroll
        for (int kk = 0; kk < 2; ++kk) {
            bf16x8 af[2], bfr[4];
#pragma unroll
            for (int i = 0; i < 2; ++i) {
                int row = wr * 32 + i * 16 + (lane & 15);
                int pp = (kk * 4 + (lane >> 4)) ^ (row & 7);
                af[i] = *(const bf16x8*)&Abuf[(row * 8 + pp) * 8];
            }
#pragma unroll
            for (int j = 0; j < 4; ++j) {
                int col = wc * 64 + j * 16 + (lane & 15);
                int pp = (kk * 4 + (lane >> 4)) ^ (col & 7);
                bfr[j] = *(const bf16x8*)&Btb[(col * 8 + pp) * 8];
            }
#pragma unroll
            for (int i = 0; i < 2; ++i)
#pragma unroll
                for (int j = 0; j < 4; ++j)
                    acc[i][j] = __builtin_amdgcn_mfma_f32_16x16x32_bf16(af[i], bfr[j], acc[i][j], 0, 0, 0);
            if (MODE == 0) {
                if (ks == 8 || ks == 9) {
                    bf16x8 b2f_[4];
#pragma unroll
                    for (int j = 0; j < 4; ++j) {
                        int col = wc * 64 + j * 16 + (lane & 15);
                        int pp = (kk * 4 + (lane >> 4)) ^ (col & 7);
                        b2f_[j] = *(const bf16x8*)&Bt2[(col * 8 + pp) * 8];
                    }
#pragma unroll
                    for (int i = 0; i < 2; ++i)
#pragma unroll
                        for (int j = 0; j < 4; ++j)
                            acc2[i][j] = __builtin_amdgcn_mfma_f32_16x16x32_bf16(af[i], b2f_[j], acc2[i][j], 0, 0, 0);
                }
            }
        }
        __syncthreads();
    }

    // ---- epilogue ----
    float scale = (MODE == 0) ? wsf[SCALE_IDX] : 0.f;
#pragma unroll
    for (int i = 0; i < 2; ++i)
#pragma unroll
        for (int j = 0; j < 4; ++j)
#pragma unroll
            for (int r = 0; r < 4; ++r) {
                int row = wr * 32 + i * 16 + ((lane >> 4) << 2) + r;
                int coll = wc * 64 + j * 16 + (lane & 15);
                float v = acc[i][j][r];
                int m = m0 + row;
                int ow = m % 28, tt2 = m / 28;
                int oh = tt2 % 28, n = tt2 / 28;
                int co = co_base + coll;
                size_t oidx = ((size_t)(n * 256 + co) * 28 + oh) * 28 + ow;
                if (MODE == 0) {
                    float dist = psq_s[row] + wsq_s[coll] - 2.0f * v + EPS_;
                    float y = v * v / dist * scale;
                    ybuf[(size_t)m * 256 + co] = f2bf(y);
                    out[oidx] = acc2[i][j][r];
                } else {
                    out[oidx] += v;
                }
            }
}

extern "C" void kernel_launch(void* const* d_in, const int* in_sizes, int n_in,
                              void* d_out, int out_size, void* d_ws, size_t ws_size,
                              hipStream_t stream) {
    const float* x       = (const float*)d_in[0];
    const float* w_yat   = (const float*)d_in[1];
    const float* alpha   = (const float*)d_in[2];
    const float* w_lin   = (const float*)d_in[3];
    const float* w_short = (const float*)d_in[4];
    float* out = (float*)d_out;
    float* wsf = (float*)d_ws;

    U16* xt = (U16*)((char*)d_ws + U16_BYTE_OFF);
    U16* yb = xt + (size_t)N_ * H_ * W_ * CIN;        // 12,845,056
    U16* B1 = yb + (size_t)M_ * COUT;                 // +6,422,528
    U16* B2 = B1 + 1152 * COUT;                       // +294,912
    U16* B3 = B2 + CIN * COUT;                        // +32,768   (B3: 589,824)

    k_prep_w   <<<3584, 256, 0, stream>>>(w_yat, w_lin, w_short, B1, B3, B2);
    k_wsq_scale<<<256,  256, 0, stream>>>(w_yat, alpha, wsf);
    k_x_t      <<<6272, 256, 0, stream>>>(x, xt);
    k_psq      <<<6272, 256, 0, stream>>>(xt, wsf);

    k_gemm<1152, 0><<<784, 256, 0, stream>>>(xt, B1, B2, wsf, yb, out);
    k_gemm<2304, 2><<<784, 256, 0, stream>>>(yb, B3, nullptr, wsf, nullptr, out);
}